// Round 3
// baseline (166.126 us; speedup 1.0000x reference)
//
#include <hip/hip_runtime.h>

typedef unsigned int u32;
typedef unsigned short u16;
typedef unsigned char u8;
typedef unsigned long long u64;

typedef __attribute__((ext_vector_type(8))) short bf16x8;
typedef __attribute__((ext_vector_type(4))) float f32x4;
typedef __attribute__((ext_vector_type(4))) u32 u32x4;

#define L_SEQ 200
#define ST_ROWS 208   // 13 tiles * 16 rows (max for L=200)
#define RND_MAX 5     // ceil(208 / 48)  (48 rows per round, 384 threads)

// R18: 6-wave half-split on top of R17 LDS staging. Diagnosis: latency-bound,
// no steady state (16 blocks/CU total work, occupancy 28%); per-wave serial
// chain = staging + ~6.75 dependent tiles. Fix: wave (a,h) = attr x seq-half
// -> serial tiles halve, waves double, staging rounds halve (48 rows/round).
// R16's vmcnt-drain bug does NOT apply: tile loop reads LDS only.
// Difference: halves combined via pN/pD LDS partials (+1.6KB), masking peeled
// to the globally-last tile only, epilogue balanced 3 outputs/wave.
// Kept: XOR-swizzled row staging (R17), DPP row16 reduce (R16), bf16 ws emb
// table gated on ws_size (R12), MFMA 16x16x32 layouts (absmax 3.05e-5).
__device__ __forceinline__ u16 f2bf(float f) {
    u32 u = __float_as_uint(f);
    return (u16)((u + 0x7FFFu + ((u >> 16) & 1u)) >> 16);  // RNE
}
__device__ __forceinline__ u32 pk2bf(float fx, float fy) {  // round-half-up pair pack
    u32 xb = __float_as_uint(fx) + 0x8000u;
    u32 yb = __float_as_uint(fy) + 0x8000u;
    return __byte_perm(xb, yb, 0x7632);
}

// sum over the 16-lane DPP row (lanes 16g..16g+15); every lane gets the total.
// row_ror:k = 0x120|k. Pure VALU: no LDS-pipe latency in the per-tile chain.
__device__ __forceinline__ float row16_sum(float v) {
    int x;
    x = __builtin_amdgcn_update_dpp(0, __float_as_int(v), 0x128, 0xF, 0xF, true);
    v += __int_as_float(x);
    x = __builtin_amdgcn_update_dpp(0, __float_as_int(v), 0x124, 0xF, 0xF, true);
    v += __int_as_float(x);
    x = __builtin_amdgcn_update_dpp(0, __float_as_int(v), 0x122, 0xF, 0xF, true);
    v += __int_as_float(x);
    x = __builtin_amdgcn_update_dpp(0, __float_as_int(v), 0x121, 0xF, 0xF, true);
    v += __int_as_float(x);
    return v;
}
__device__ __forceinline__ float wave_sumf(float v) {
    v = row16_sum(v);
    v += __shfl_xor(v, 16, 64);
    v += __shfl_xor(v, 32, 64);
    return v;
}

// ws layout (bytes): [0,24576) bf16 B-frag image; [24576,40960) len[Bn];
// [40960, 40960+Vn*128) bf16 emb table -- ONLY if ws_size permits (doConv).
__global__ __launch_bounds__(256) void etna_prep(const void* __restrict__ xmask,
                                                 const float* __restrict__ tranW,
                                                 const float* __restrict__ emb,
                                                 void* __restrict__ ws, int Bn, int Vn,
                                                 int doConv) {
    const int tid = threadIdx.x;
    const int bid = blockIdx.x;

    // emb f32 -> bf16 (grid-stride, coalesced u64 stores), gated on ws_size
    if (doConv) {
        u64* dst = (u64*)((char*)ws + 40960);
        const float4* src = (const float4*)emb;
        int ng = Vn * 16;
        for (int i = bid * 256 + tid; i < ng; i += gridDim.x * 256) {
            float4 v = src[i];
            u64 lo = pk2bf(v.x, v.y);
            u64 hi = pk2bf(v.z, v.w);
            dst[i] = lo | (hi << 32);
        }
    }

    if (bid < 48) {
        // B-frag image: element j of frag (a,c,kh,lane) =
        // tranW[a][kh*32+(lane>>4)*8+j][c*16+(lane&15)]  (contiguous writes)
        int it = bid * 256 + tid;
        int jj = it & 7;
        int ln = (it >> 3) & 63;
        int kh = (it >> 9) & 1;
        int c = (it >> 10) & 3;
        int a = it >> 12;
        int k = kh * 32 + (ln >> 4) * 8 + jj;
        int n = c * 16 + (ln & 15);
        ((u16*)ws)[it] = f2bf(tranW[a * 4096 + k * 64 + n]);
        return;
    }

    // x_mask encoding detection (first 800 bytes; safe for u8/bf16/f32/i32)
    const int wv = tid >> 6;
    const int lane = tid & 63;
    int esz;
    {
        u32 accF = 0, acc0 = 0, accO = 0;
#pragma unroll
        for (int k = 0; k < 4; ++k) {
            int i = lane + 64 * k;
            u32 w = (i < 200) ? ((const u32*)xmask)[i] : 0u;
            accF |= (w & 0xFEFEFEFEu);
            acc0 |= (w & 0x000000FFu);
            accO |= (w & 0xFFFFFF00u);
        }
        bool isFloat = __ballot(accF != 0) != 0;
        bool hasB0   = __ballot(acc0 != 0) != 0;
        bool hasOdd  = __ballot(accO != 0) != 0;
        esz = isFloat ? (hasB0 ? 2 : 4) : (hasOdd ? 1 : 4);
    }
    int s = (bid - 48) * 4 + wv;  // one wave per sample
    if (s < Bn) {
        int len = 0;
        int mbase = s * L_SEQ;
#pragma unroll
        for (int c4 = 0; c4 < 4; ++c4) {
            int l = c4 * 64 + lane;
            bool v = false;
            if (l < L_SEQ) {
                int off = mbase + l;
                if (esz == 1)      v = ((const u8*)xmask)[off] != 0;
                else if (esz == 2) v = ((const u16*)xmask)[off] != 0;
                else               v = ((const u32*)xmask)[off] != 0;
            }
            len += (int)__popcll(__ballot(v));
        }
        if (lane == 0) ((int*)((char*)ws + 24576))[s] = len;
    }
}

// ---- main: block = 1 sample = 6 waves; wave w: attr a = w%3, half h = w/3 ---
// TAB=true: stage bf16 rows from ws table. TAB=false: stage f32 rows from emb
// and pack (fallback when ws_size too small for the table).
template <bool TAB>
__global__ __launch_bounds__(384, 4) void etna_mfma(
    const int* __restrict__ x, const float* __restrict__ ob,
    const float* __restrict__ emb, const float* __restrict__ tranb,
    const float* __restrict__ attW, const float* __restrict__ attb,
    const float* __restrict__ W0, const float* __restrict__ W1,
    const float* __restrict__ W2, float* __restrict__ out,
    const void* __restrict__ ws, int Vn) {
    __shared__ __align__(16) float ldsf[ST_ROWS * 32];  // staged rows, swizzled
    __shared__ float pN[2][3][64];   // per-half partial numerators
    __shared__ float pD[2][3];       // per-half partial denominators
    __shared__ float rep[3][64];     // post-tanh user rep
    char* ldsb = (char*)ldsf;

    const int tid = threadIdx.x;
    const int w = tid >> 6;
    const int a = w % 3;        // attribute
    const int h = w / 3;        // sequence half
    const int lane = tid & 63;
    const int col = lane & 15;  // A row m / B+D col n
    const int g = lane >> 4;    // k-chunk / D row group
    const int b = blockIdx.x;

    // this attr's B-frags: 8 coalesced dwordx4 loads (L2-hot image) -> 32 VGPRs
    const u16* wsBf = (const u16*)ws;
    bf16x8 Bf[4][2];
#pragma unroll
    for (int c = 0; c < 4; ++c)
#pragma unroll
        for (int kh = 0; kh < 2; ++kh)
            Bf[c][kh] = *(const bf16x8*)&wsBf[(((a * 4 + c) * 2 + kh) * 64 + lane) * 8];

    const int len = ((const int*)((const char*)ws + 24576))[b];
    const u16* wsEmb = (const u16*)((const char*)ws + 40960);

    // per-lane constants (C-layout dim = c*16+col); LOG2E folded into AW/AB
    const float LOG2E = 1.44269504088896f;
    float TB[4], AW[4];
#pragma unroll
    for (int c = 0; c < 4; ++c) {
        TB[c] = tranb[a * 64 + c * 16 + col];
        AW[c] = attW[a * 64 + c * 16 + col] * LOG2E;
    }
    const float AB = attb[a] * LOG2E;

    const int* xrow = x + b * L_SEQ;
    const int nt = (len + 15) >> 4;         // tiles
    const int stRows = nt << 4;             // rows to stage
    const int rounds = (stRows + 47) / 48;  // 48 rows/round (384 lanes * 16B)

    // ---- cooperative staging: rows [0,stRows) -> LDS, swizzled ----
    // round j, this lane: row p = j*48 + w*8 + (lane>>3), 16B chunk ch=lane&7.
    // physical byte within row: (ch*16) ^ ((p&7)<<4)   [G4 XOR swizzle]
    // Rows >= len stage whatever x[q] points at (valid vocab rows); they are
    // killed by the s=0 mask in the globally-last tile -- no id select needed.
    const int sp = w * 8 + (lane >> 3);
    const int ch = lane & 7;

    // ids up-front: static-indexed array (rule #20); issued before any row
    // gather so the staging pipeline never waits through an id load (R16 bug).
    int ids[RND_MAX];
#pragma unroll
    for (int j = 0; j < RND_MAX; ++j) {
        ids[j] = 0;
        if (j < rounds) {
            int p = j * 48 + sp;
            int q = (p < L_SEQ) ? p : (L_SEQ - 1);
            int idv = xrow[q];
            ids[j] = max(0, min(idv, Vn - 1));  // OOB-crash insurance only
        }
    }

    if (TAB) {
        // depth-3 pipeline: issue load j, write j-2 (vmcnt keeps 2 in flight)
        bf16x8 stq[3];
#pragma unroll
        for (int j = 0; j < RND_MAX + 2; ++j) {
            if (j < RND_MAX && j < rounds)
                stq[j % 3] = ((const bf16x8*)(wsEmb + (size_t)ids[j] * 64))[ch];
            int k = j - 2;
            if (k >= 0 && k < rounds) {
                int p = k * 48 + sp;
                if (p < stRows) {
                    u32 off = (u32)p * 128 + (u32)((ch * 16) ^ ((p & 7) << 4));
                    *(bf16x8*)(ldsb + off) = stq[k % 3];
                }
            }
        }
    } else {
        // fallback: f32 rows, pack to bf16 (correctness path; depth-1)
        for (int j = 0; j < rounds; ++j) {
            int p = j * 48 + sp;
            if (p < stRows) {
                const float4* ep4 = (const float4*)(emb + (size_t)ids[j] * 64);
                float4 q0 = ep4[2 * ch], q1 = ep4[2 * ch + 1];
                u32x4 wv_;
                wv_.x = pk2bf(q0.x, q0.y);
                wv_.y = pk2bf(q0.z, q0.w);
                wv_.z = pk2bf(q1.x, q1.y);
                wv_.w = pk2bf(q1.z, q1.w);
                u32 off = (u32)p * 128 + (u32)((ch * 16) ^ ((p & 7) << 4));
                *(bf16x8*)(ldsb + off) = __builtin_bit_cast(bf16x8, wv_);
            }
        }
    }
    __syncthreads();

    // ---- this wave's tile range: half h of [0, nt) ----
    const int nth = (nt + 1) >> 1;
    const int tA = h * nth;
    const int tB = min(nt, tA + nth);
    const bool ownLast = (tB == nt) && (tA < tB);  // this wave owns tile nt-1

    // swizzle term (col&7)<<4 is per-lane constant (rows advance by 16).
    const u32 c0 = (u32)((g * 16) ^ ((col & 7) << 4));
    u32 ra = (u32)(tA * 16 + col) * 128 + c0;

    float NUM[4] = {0.f, 0.f, 0.f, 0.f};
    float DEN = 0.f;

    bf16x8 a0, a1;
    if (tA < tB) {
        a0 = *(const bf16x8*)(ldsb + ra);
        a1 = *(const bf16x8*)(ldsb + (ra ^ 64u));
    }

    for (int t = tA; t < tB; ++t) {
        bf16x8 n0 = a0, n1 = a1;
        if (t + 1 < tB) {
            u32 rn = ra + 2048u;
            n0 = *(const bf16x8*)(ldsb + rn);
            n1 = *(const bf16x8*)(ldsb + (rn ^ 64u));
        }
        ra += 2048u;

        f32x4 E[4];
#pragma unroll
        for (int c = 0; c < 4; ++c) {
            f32x4 cc = {TB[c], TB[c], TB[c], TB[c]};
            cc = __builtin_amdgcn_mfma_f32_16x16x32_bf16(a0, Bf[c][0], cc, 0, 0, 0);
            cc = __builtin_amdgcn_mfma_f32_16x16x32_bf16(a1, Bf[c][1], cc, 0, 0, 0);
            E[c].x = fmaxf(cc.x, 0.f);
            E[c].y = fmaxf(cc.y, 0.f);
            E[c].z = fmaxf(cc.z, 0.f);
            E[c].w = fmaxf(cc.w, 0.f);
        }
        float p0 = E[0].x * AW[0] + E[1].x * AW[1] + E[2].x * AW[2] + E[3].x * AW[3];
        float p1 = E[0].y * AW[0] + E[1].y * AW[1] + E[2].y * AW[2] + E[3].y * AW[3];
        float p2 = E[0].z * AW[0] + E[1].z * AW[1] + E[2].z * AW[2] + E[3].z * AW[3];
        float p3 = E[0].w * AW[0] + E[1].w * AW[1] + E[2].w * AW[2] + E[3].w * AW[3];
        p0 = row16_sum(p0);
        p1 = row16_sum(p1);
        p2 = row16_sum(p2);
        p3 = row16_sum(p3);

        float s0 = exp2f(fmaxf(p0 + AB, 0.f));
        float s1 = exp2f(fmaxf(p1 + AB, 0.f));
        float s2 = exp2f(fmaxf(p2 + AB, 0.f));
        float s3 = exp2f(fmaxf(p3 + AB, 0.f));
        if (ownLast && t == nt - 1) {  // wave-uniform branch: only last tile
            int lrow = (t << 4) + 4 * g;
            s0 = (lrow + 0 < len) ? s0 : 0.f;
            s1 = (lrow + 1 < len) ? s1 : 0.f;
            s2 = (lrow + 2 < len) ? s2 : 0.f;
            s3 = (lrow + 3 < len) ? s3 : 0.f;
        }
        DEN += s0 + s1 + s2 + s3;
#pragma unroll
        for (int c = 0; c < 4; ++c)
            NUM[c] += s0 * E[c].x + s1 * E[c].y + s2 * E[c].z + s3 * E[c].w;

        a0 = n0;
        a1 = n1;
    }

    // fold row-groups -> per-(half,attr) partials
    {
        float d = DEN;
        d += __shfl_xor(d, 16, 64);
        d += __shfl_xor(d, 32, 64);
        if (lane == 0) pD[h][a] = d;
#pragma unroll
        for (int c = 0; c < 4; ++c) {
            float v = NUM[c];
            v += __shfl_xor(v, 16, 64);
            v += __shfl_xor(v, 32, 64);
            if (g == 0) pN[h][a][c * 16 + col] = v;
        }
    }
    __syncthreads();

    // combine halves + tanh (waves h==0; one per attr)
    if (h == 0) {
        float dt = pD[0][a] + pD[1][a];
        float rden = 1.0f / fmaxf(dt, 1e-20f);  // den >= 1 when len >= 1
        float nv = pN[0][a][lane] + pN[1][a][lane];
        rep[a][lane] = tanhf(nv * rden);
    }
    __syncthreads();

    // epilogue balanced: wave w -> outputs {w, w+6, w+12} (3 each).
    // torch interleave u[3d+aa]=rep[aa][d]; seg s covers u[64s:64s+64] @ Ws
#pragma unroll
    for (int r = 0; r < 3; ++r) {
        int o = w + r * 6;
        int seg = (o < 2) ? 0 : ((o < 8) ? 1 : 2);
        int k = o - ((seg == 0) ? 0 : ((seg == 1) ? 2 : 8));
        int AL = (seg == 0) ? 2 : ((seg == 1) ? 6 : 10);
        const float* Wp = (seg == 0) ? W0 : ((seg == 1) ? W1 : W2);
        int gg = seg * 64 + lane;
        float v = rep[gg % 3][gg / 3];
        float pz = wave_sumf(v * Wp[lane * AL + k]);
        if (lane == 0) out[b * 18 + o] = pz * ob[b * 18 + o];
    }
}

extern "C" void kernel_launch(void* const* d_in, const int* in_sizes, int n_in,
                              void* d_out, int out_size, void* d_ws, size_t ws_size,
                              hipStream_t stream) {
    const int* x = (const int*)d_in[0];
    const void* xmask = d_in[1];
    // d_in[2] = y : unused
    const float* ob = (const float*)d_in[3];
    const float* emb = (const float*)d_in[4];
    const float* tranW = (const float*)d_in[5];
    const float* tranb = (const float*)d_in[6];
    const float* attW = (const float*)d_in[7];
    const float* attb = (const float*)d_in[8];
    const float* W0 = (const float*)d_in[9];
    const float* W1 = (const float*)d_in[10];
    const float* W2 = (const float*)d_in[11];

    const int Bn = in_sizes[0] / L_SEQ;  // 4096
    const int Vn = in_sizes[4] / 64;     // vocab rows

    // gate the 12.8MB emb bf16 table on the ACTUAL workspace size (constant
    // across calls -> same work every launch, graph-capture safe)
    const size_t need = 40960 + (size_t)Vn * 128;
    const int useTab = (ws_size >= need) ? 1 : 0;

    etna_prep<<<48 + (Bn + 3) / 4, 256, 0, stream>>>(xmask, tranW, emb, d_ws, Bn, Vn, useTab);
    if (useTab)
        etna_mfma<true><<<Bn, 384, 0, stream>>>(x, ob, emb, tranb, attW, attb,
                                                W0, W1, W2, (float*)d_out, d_ws, Vn);
    else
        etna_mfma<false><<<Bn, 384, 0, stream>>>(x, ob, emb, tranb, attW, attb,
                                                 W0, W1, W2, (float*)d_out, d_ws, Vn);
}

// Round 4
// 144.059 us; speedup vs baseline: 1.1532x; 1.1532x over previous
//
#include <hip/hip_runtime.h>

typedef unsigned int u32;
typedef unsigned short u16;
typedef unsigned char u8;
typedef unsigned long long u64;

typedef __attribute__((ext_vector_type(8))) short bf16x8;
typedef __attribute__((ext_vector_type(4))) float f32x4;
typedef __attribute__((ext_vector_type(4))) u32 u32x4;

#define L_SEQ 200
#define ST_ROWS 208   // 13 tiles * 16 rows (max for L=200)
#define RND_MAX 9     // ceil(208 / 24)  (24 rows/round, 192 threads)

// R19: global_load_lds staging. Post-mortems: R18's junk rows = +4MB fetch
// (reverted); occupancy flat at 2x waves -> not wave-limited; R17's depth-3
// register staging = ~3 serial L3 latencies. Fix: stage via
// __builtin_amdgcn_global_load_lds (per-lane global src, linear LDS dest,
// rule #21 inverse-swizzled source chunk: p&7 == lane>>3 since row blocks are
// 8-aligned). All 9 ids load first (parallel), then all 9 DMAs issue
// back-to-back -> one L3 latency per stage, zero data VGPRs.
// Kept: R17 swizzled LDS tile loop (proven, ~0 conflicts), DPP row16 reduce,
// bf16 ws emb table gated on ws_size, MFMA 16x16x32 layouts (absmax 3.05e-5).
// New: balanced epilogue (6 outputs/wave), last-tile-only len mask.
__device__ __forceinline__ u16 f2bf(float f) {
    u32 u = __float_as_uint(f);
    return (u16)((u + 0x7FFFu + ((u >> 16) & 1u)) >> 16);  // RNE
}
__device__ __forceinline__ u32 pk2bf(float fx, float fy) {  // round-half-up pair pack
    u32 xb = __float_as_uint(fx) + 0x8000u;
    u32 yb = __float_as_uint(fy) + 0x8000u;
    return __byte_perm(xb, yb, 0x7632);
}

__device__ __forceinline__ void gld_lds16(const void* g, void* l) {
    __builtin_amdgcn_global_load_lds(
        (const __attribute__((address_space(1))) u32*)g,
        (__attribute__((address_space(3))) u32*)l, 16, 0, 0);
}

// sum over the 16-lane DPP row (lanes 16g..16g+15); every lane gets the total.
// row_ror:k = 0x120|k. Pure VALU: no LDS-pipe latency in the per-tile chain.
__device__ __forceinline__ float row16_sum(float v) {
    int x;
    x = __builtin_amdgcn_update_dpp(0, __float_as_int(v), 0x128, 0xF, 0xF, true);
    v += __int_as_float(x);
    x = __builtin_amdgcn_update_dpp(0, __float_as_int(v), 0x124, 0xF, 0xF, true);
    v += __int_as_float(x);
    x = __builtin_amdgcn_update_dpp(0, __float_as_int(v), 0x122, 0xF, 0xF, true);
    v += __int_as_float(x);
    x = __builtin_amdgcn_update_dpp(0, __float_as_int(v), 0x121, 0xF, 0xF, true);
    v += __int_as_float(x);
    return v;
}
__device__ __forceinline__ float wave_sumf(float v) {
    v = row16_sum(v);
    v += __shfl_xor(v, 16, 64);
    v += __shfl_xor(v, 32, 64);
    return v;
}

// ws layout (bytes): [0,24576) bf16 B-frag image; [24576,40960) len[Bn];
// [40960, 40960+Vn*128) bf16 emb table -- ONLY if ws_size permits (doConv).
__global__ __launch_bounds__(256) void etna_prep(const void* __restrict__ xmask,
                                                 const float* __restrict__ tranW,
                                                 const float* __restrict__ emb,
                                                 void* __restrict__ ws, int Bn, int Vn,
                                                 int doConv) {
    const int tid = threadIdx.x;
    const int bid = blockIdx.x;

    // emb f32 -> bf16 (grid-stride, coalesced u64 stores), gated on ws_size
    if (doConv) {
        u64* dst = (u64*)((char*)ws + 40960);
        const float4* src = (const float4*)emb;
        int ng = Vn * 16;
        for (int i = bid * 256 + tid; i < ng; i += gridDim.x * 256) {
            float4 v = src[i];
            u64 lo = pk2bf(v.x, v.y);
            u64 hi = pk2bf(v.z, v.w);
            dst[i] = lo | (hi << 32);
        }
    }

    if (bid < 48) {
        // B-frag image: element j of frag (a,c,kh,lane) =
        // tranW[a][kh*32+(lane>>4)*8+j][c*16+(lane&15)]  (contiguous writes)
        int it = bid * 256 + tid;
        int jj = it & 7;
        int ln = (it >> 3) & 63;
        int kh = (it >> 9) & 1;
        int c = (it >> 10) & 3;
        int a = it >> 12;
        int k = kh * 32 + (ln >> 4) * 8 + jj;
        int n = c * 16 + (ln & 15);
        ((u16*)ws)[it] = f2bf(tranW[a * 4096 + k * 64 + n]);
        return;
    }

    // x_mask encoding detection (first 800 bytes; safe for u8/bf16/f32/i32)
    const int wv = tid >> 6;
    const int lane = tid & 63;
    int esz;
    {
        u32 accF = 0, acc0 = 0, accO = 0;
#pragma unroll
        for (int k = 0; k < 4; ++k) {
            int i = lane + 64 * k;
            u32 w = (i < 200) ? ((const u32*)xmask)[i] : 0u;
            accF |= (w & 0xFEFEFEFEu);
            acc0 |= (w & 0x000000FFu);
            accO |= (w & 0xFFFFFF00u);
        }
        bool isFloat = __ballot(accF != 0) != 0;
        bool hasB0   = __ballot(acc0 != 0) != 0;
        bool hasOdd  = __ballot(accO != 0) != 0;
        esz = isFloat ? (hasB0 ? 2 : 4) : (hasOdd ? 1 : 4);
    }
    int s = (bid - 48) * 4 + wv;  // one wave per sample
    if (s < Bn) {
        int len = 0;
        int mbase = s * L_SEQ;
#pragma unroll
        for (int c4 = 0; c4 < 4; ++c4) {
            int l = c4 * 64 + lane;
            bool v = false;
            if (l < L_SEQ) {
                int off = mbase + l;
                if (esz == 1)      v = ((const u8*)xmask)[off] != 0;
                else if (esz == 2) v = ((const u16*)xmask)[off] != 0;
                else               v = ((const u32*)xmask)[off] != 0;
            }
            len += (int)__popcll(__ballot(v));
        }
        if (lane == 0) ((int*)((char*)ws + 24576))[s] = len;
    }
}

// ---- main: block = 1 sample = 3 waves; wave owns attr a = wave id ----------
// TAB=true: DMA-stage bf16 rows from ws table. TAB=false: register-stage f32
// rows from emb and pack (fallback when ws_size too small for the table).
template <bool TAB>
__global__ __launch_bounds__(192, 4) void etna_mfma(
    const int* __restrict__ x, const float* __restrict__ ob,
    const float* __restrict__ emb, const float* __restrict__ tranb,
    const float* __restrict__ attW, const float* __restrict__ attb,
    const float* __restrict__ W0, const float* __restrict__ W1,
    const float* __restrict__ W2, float* __restrict__ out,
    const void* __restrict__ ws, int Vn) {
    __shared__ __align__(16) float ldsf[ST_ROWS * 32];  // staged rows, swizzled
    __shared__ float rep[3][64];                        // post-tanh user rep
    char* ldsb = (char*)ldsf;

    const int tid = threadIdx.x;
    const int a = tid >> 6;     // wave = attribute
    const int lane = tid & 63;
    const int col = lane & 15;  // A row m / B+D col n
    const int g = lane >> 4;    // k-chunk / D row group
    const int b = blockIdx.x;

    // this attr's B-frags: 8 coalesced dwordx4 loads (L2-hot image) -> 32 VGPRs
    const u16* wsBf = (const u16*)ws;
    bf16x8 Bf[4][2];
#pragma unroll
    for (int c = 0; c < 4; ++c)
#pragma unroll
        for (int kh = 0; kh < 2; ++kh)
            Bf[c][kh] = *(const bf16x8*)&wsBf[(((a * 4 + c) * 2 + kh) * 64 + lane) * 8];

    const int len = ((const int*)((const char*)ws + 24576))[b];
    const u16* wsEmb = (const u16*)((const char*)ws + 40960);

    // per-lane constants (C-layout dim = c*16+col); LOG2E folded into AW/AB
    const float LOG2E = 1.44269504088896f;
    float TB[4], AW[4];
#pragma unroll
    for (int c = 0; c < 4; ++c) {
        TB[c] = tranb[a * 64 + c * 16 + col];
        AW[c] = attW[a * 64 + c * 16 + col] * LOG2E;
    }
    const float AB = attb[a] * LOG2E;

    const int* xrow = x + b * L_SEQ;
    const int nt = (len + 15) >> 4;         // tiles
    const int stRows = nt << 4;             // rows to stage
    const int rounds = (stRows + 23) / 24;  // 24 rows/round (192 lanes * 16B)

    // ---- cooperative staging: rows [0,stRows) -> LDS, swizzled ----
    // round j, this lane: row p = j*24 + a*8 + (lane>>3), dest chunk ch=lane&7.
    // Row blocks are 8-aligned -> p&7 == lane>>3 (per-lane constant).
    // Physical LDS layout: row p, phys chunk c holds row chunk c ^ (p&7);
    // DMA writes LDS linearly (base + lane*16), so the SOURCE chunk is
    // inverse-swizzled: src chunk = ch ^ (lane>>3).   [rule #21]
    const int sp = a * 8 + (lane >> 3);
    const int ch = lane & 7;
    const u32 srcChunkOff = (u32)((ch ^ (lane >> 3)) << 4);

    // ids up-front: 9 parallel coalesced loads (static-indexed, rule #20).
    // Masked rows (p>=len) -> id 0 (L1-hot zero row) -- NOT junk gathers (R18).
    int ids[RND_MAX];
#pragma unroll
    for (int j = 0; j < RND_MAX; ++j) {
        ids[j] = 0;
        if (j < rounds) {
            int p = j * 24 + sp;
            int q = (p < L_SEQ) ? p : (L_SEQ - 1);
            int idv = xrow[q];
            idv = max(0, min(idv, Vn - 1));
            ids[j] = (p < len) ? idv : 0;
        }
    }

    if (TAB) {
        // issue ALL rounds back-to-back: one DMA per wave per round, no data
        // VGPRs, ~24 scattered 1KB DMAs in flight per block -> one L3 latency.
#pragma unroll
        for (int j = 0; j < RND_MAX; ++j) {
            if (j < rounds) {
                int p = j * 24 + sp;
                const char* gsrc =
                    (const char*)wsEmb + (size_t)ids[j] * 128 + srcChunkOff;
                char* ldst = ldsb + (u32)(j * 24 + a * 8) * 128;  // wave-uniform
                if (p < stRows)  // EXEC-masks the partial last round
                    gld_lds16(gsrc, ldst);
            }
        }
    } else {
        // fallback: f32 rows, pack to bf16 (correctness path; register-staged)
        for (int j = 0; j < rounds; ++j) {
            int p = j * 24 + sp;
            if (p < stRows) {
                const float4* ep4 = (const float4*)(emb + (size_t)ids[j] * 64);
                float4 q0 = ep4[2 * ch], q1 = ep4[2 * ch + 1];
                u32x4 wv_;
                wv_.x = pk2bf(q0.x, q0.y);
                wv_.y = pk2bf(q0.z, q0.w);
                wv_.z = pk2bf(q1.x, q1.y);
                wv_.w = pk2bf(q1.z, q1.w);
                u32 off = (u32)p * 128 + (u32)((ch * 16) ^ ((p & 7) << 4));
                *(bf16x8*)(ldsb + off) = __builtin_bit_cast(bf16x8, wv_);
            }
        }
    }
    __syncthreads();  // compiler drains vmcnt(0) -> all DMA rows landed

    // ---- tile loop: A-frags from LDS. swizzle term (col&7)<<4 is per-lane
    // constant (rows advance by 16 -> p&7 == col&7). r1 addr = r0 addr ^ 64.
    const u32 c0 = (u32)((g * 16) ^ ((col & 7) << 4));
    u32 ra = (u32)col * 128 + c0;

    float NUM[4] = {0.f, 0.f, 0.f, 0.f};
    float DEN = 0.f;

    bf16x8 a0 = *(const bf16x8*)(ldsb + ra);
    bf16x8 a1 = *(const bf16x8*)(ldsb + (ra ^ 64u));

    for (int t = 0; t < nt; ++t) {
        bf16x8 n0 = a0, n1 = a1;
        if (t + 1 < nt) {
            u32 rn = ra + 2048u;
            n0 = *(const bf16x8*)(ldsb + rn);
            n1 = *(const bf16x8*)(ldsb + (rn ^ 64u));
        }
        ra += 2048u;

        f32x4 E[4];
#pragma unroll
        for (int c = 0; c < 4; ++c) {
            f32x4 cc = {TB[c], TB[c], TB[c], TB[c]};
            cc = __builtin_amdgcn_mfma_f32_16x16x32_bf16(a0, Bf[c][0], cc, 0, 0, 0);
            cc = __builtin_amdgcn_mfma_f32_16x16x32_bf16(a1, Bf[c][1], cc, 0, 0, 0);
            E[c].x = fmaxf(cc.x, 0.f);
            E[c].y = fmaxf(cc.y, 0.f);
            E[c].z = fmaxf(cc.z, 0.f);
            E[c].w = fmaxf(cc.w, 0.f);
        }
        float p0 = E[0].x * AW[0] + E[1].x * AW[1] + E[2].x * AW[2] + E[3].x * AW[3];
        float p1 = E[0].y * AW[0] + E[1].y * AW[1] + E[2].y * AW[2] + E[3].y * AW[3];
        float p2 = E[0].z * AW[0] + E[1].z * AW[1] + E[2].z * AW[2] + E[3].z * AW[3];
        float p3 = E[0].w * AW[0] + E[1].w * AW[1] + E[2].w * AW[2] + E[3].w * AW[3];
        p0 = row16_sum(p0);
        p1 = row16_sum(p1);
        p2 = row16_sum(p2);
        p3 = row16_sum(p3);

        float s0 = exp2f(fmaxf(p0 + AB, 0.f));
        float s1 = exp2f(fmaxf(p1 + AB, 0.f));
        float s2 = exp2f(fmaxf(p2 + AB, 0.f));
        float s3 = exp2f(fmaxf(p3 + AB, 0.f));
        if (t == nt - 1) {  // wave-uniform: only the last (partial) tile masks
            int lrow = (t << 4) + 4 * g;
            s0 = (lrow + 0 < len) ? s0 : 0.f;
            s1 = (lrow + 1 < len) ? s1 : 0.f;
            s2 = (lrow + 2 < len) ? s2 : 0.f;
            s3 = (lrow + 3 < len) ? s3 : 0.f;
        }
        DEN += s0 + s1 + s2 + s3;
#pragma unroll
        for (int c = 0; c < 4; ++c)
            NUM[c] += s0 * E[c].x + s1 * E[c].y + s2 * E[c].z + s3 * E[c].w;

        a0 = n0;
        a1 = n1;
    }

    // fold row-groups -> wave totals; write this attr's rep
    {
        float d = DEN;
        d += __shfl_xor(d, 16, 64);
        d += __shfl_xor(d, 32, 64);
        float rden = 1.0f / fmaxf(d, 1e-20f);  // den >= 1 when len >= 1
#pragma unroll
        for (int c = 0; c < 4; ++c) {
            float v = NUM[c];
            v += __shfl_xor(v, 16, 64);
            v += __shfl_xor(v, 32, 64);
            if (g == 0) rep[a][c * 16 + col] = tanhf(v * rden);
        }
    }
    __syncthreads();

    // epilogue balanced: wave a -> outputs {a, a+3, ..., a+15} (6 each).
    // torch interleave u[3d+aa]=rep[aa][d]; seg s covers u[64s:64s+64] @ Ws
#pragma unroll
    for (int r = 0; r < 6; ++r) {
        int o = a + 3 * r;
        int seg = (o < 2) ? 0 : ((o < 8) ? 1 : 2);
        int k = o - ((seg == 0) ? 0 : ((seg == 1) ? 2 : 8));
        int AL = (seg == 0) ? 2 : ((seg == 1) ? 6 : 10);
        const float* Wp = (seg == 0) ? W0 : ((seg == 1) ? W1 : W2);
        int gg = seg * 64 + lane;
        float v = rep[gg % 3][gg / 3];
        float pz = wave_sumf(v * Wp[lane * AL + k]);
        if (lane == 0) out[b * 18 + o] = pz * ob[b * 18 + o];
    }
}

extern "C" void kernel_launch(void* const* d_in, const int* in_sizes, int n_in,
                              void* d_out, int out_size, void* d_ws, size_t ws_size,
                              hipStream_t stream) {
    const int* x = (const int*)d_in[0];
    const void* xmask = d_in[1];
    // d_in[2] = y : unused
    const float* ob = (const float*)d_in[3];
    const float* emb = (const float*)d_in[4];
    const float* tranW = (const float*)d_in[5];
    const float* tranb = (const float*)d_in[6];
    const float* attW = (const float*)d_in[7];
    const float* attb = (const float*)d_in[8];
    const float* W0 = (const float*)d_in[9];
    const float* W1 = (const float*)d_in[10];
    const float* W2 = (const float*)d_in[11];

    const int Bn = in_sizes[0] / L_SEQ;  // 4096
    const int Vn = in_sizes[4] / 64;     // vocab rows

    // gate the 12.8MB emb bf16 table on the ACTUAL workspace size (constant
    // across calls -> same work every launch, graph-capture safe)
    const size_t need = 40960 + (size_t)Vn * 128;
    const int useTab = (ws_size >= need) ? 1 : 0;

    etna_prep<<<48 + (Bn + 3) / 4, 256, 0, stream>>>(xmask, tranW, emb, d_ws, Bn, Vn, useTab);
    if (useTab)
        etna_mfma<true><<<Bn, 192, 0, stream>>>(x, ob, emb, tranb, attW, attb,
                                                W0, W1, W2, (float*)d_out, d_ws, Vn);
    else
        etna_mfma<false><<<Bn, 192, 0, stream>>>(x, ob, emb, tranb, attW, attb,
                                                 W0, W1, W2, (float*)d_out, d_ws, Vn);
}